// Round 3
// baseline (23133.353 us; speedup 1.0000x reference)
//
#include <hip/hip_runtime.h>
#include <cstddef>

#define D_  1024
#define S_  512
#define B_  8
#define H_  16
#define HD_ 64
#define L_  12
#define DF_ 4096
#define M_  (B_ * S_)   // 4096 rows

// ---------------------------------------------------------------- LayerNorm
// one block per row of 1024; 256 threads, float4 per thread
__launch_bounds__(256)
__global__ void ln_rows(const float* __restrict__ x, const float* __restrict__ g,
                        const float* __restrict__ be, float* __restrict__ y)
{
    __shared__ float red[8];
    const int t = threadIdx.x;
    const float* xr = x + (size_t)blockIdx.x * D_;
    float4 v = *reinterpret_cast<const float4*>(&xr[t * 4]);
    float s  = v.x + v.y + v.z + v.w;
    float s2 = v.x * v.x + v.y * v.y + v.z * v.z + v.w * v.w;
#pragma unroll
    for (int o = 32; o > 0; o >>= 1) {
        s  += __shfl_xor(s, o);
        s2 += __shfl_xor(s2, o);
    }
    const int w = t >> 6, lane = t & 63;
    if (lane == 0) { red[w] = s; red[4 + w] = s2; }
    __syncthreads();
    s  = red[0] + red[1] + red[2] + red[3];
    s2 = red[4] + red[5] + red[6] + red[7];
    const float m   = s * (1.f / D_);
    const float var = s2 * (1.f / D_) - m * m;
    const float rs  = rsqrtf(var + 1e-5f);
    float4 gv = *reinterpret_cast<const float4*>(&g[t * 4]);
    float4 bv = *reinterpret_cast<const float4*>(&be[t * 4]);
    float4 o4;
    o4.x = (v.x - m) * rs * gv.x + bv.x;
    o4.y = (v.y - m) * rs * gv.y + bv.y;
    o4.z = (v.z - m) * rs * gv.z + bv.z;
    o4.w = (v.w - m) * rs * gv.w + bv.w;
    *reinterpret_cast<float4*>(&y[(size_t)blockIdx.x * D_ + t * 4]) = o4;
}

// ---------------------------------------------------------------- main GEMM
// C[M,N] = A[M,K] @ W[K,N] (+bias, epilogue). Tile 128x64, BK=16.
// EPI 1: out = relu(acc + bias)
// EPI 2: out = res + acc + bias
// EPI 3: out = (acc + bias) * scale, remapped to q/k/v layout [B,H,S,HD]
template<int EPI>
__launch_bounds__(256)
__global__ void gemm_tile(const float* __restrict__ A, const float* __restrict__ W,
                          const float* __restrict__ bias, const float* __restrict__ res,
                          float* __restrict__ out, int M, int N, int K, float scale)
{
    __shared__ float As[16][132];   // transposed A tile [k][m]
    __shared__ float Bs[16][68];    // B tile [k][n]
    const int t  = threadIdx.x;
    const int tx = t & 15, ty = t >> 4;
    const int m0 = blockIdx.y * 128;
    const int n0 = blockIdx.x * 64;

    float c[8][4];
#pragma unroll
    for (int i = 0; i < 8; ++i)
#pragma unroll
        for (int j = 0; j < 4; ++j) c[i][j] = 0.f;

    for (int k0 = 0; k0 < K; k0 += 16) {
#pragma unroll
        for (int it = 0; it < 2; ++it) {           // A: 128x16 = 512 float4
            int idx = t + it * 256;
            int r   = idx >> 2;
            int c4  = (idx & 3) << 2;
            float4 av = *reinterpret_cast<const float4*>(&A[(size_t)(m0 + r) * K + k0 + c4]);
            As[c4 + 0][r] = av.x;
            As[c4 + 1][r] = av.y;
            As[c4 + 2][r] = av.z;
            As[c4 + 3][r] = av.w;
        }
        {                                           // B: 16x64 = 256 float4
            int r  = t >> 4;
            int c4 = (t & 15) << 2;
            *reinterpret_cast<float4*>(&Bs[r][c4]) =
                *reinterpret_cast<const float4*>(&W[(size_t)(k0 + r) * N + n0 + c4]);
        }
        __syncthreads();
#pragma unroll
        for (int kk = 0; kk < 16; ++kk) {
            float a[8], b[4];
            *reinterpret_cast<float4*>(&a[0]) = *reinterpret_cast<const float4*>(&As[kk][ty * 8]);
            *reinterpret_cast<float4*>(&a[4]) = *reinterpret_cast<const float4*>(&As[kk][ty * 8 + 4]);
            *reinterpret_cast<float4*>(&b[0]) = *reinterpret_cast<const float4*>(&Bs[kk][tx * 4]);
#pragma unroll
            for (int i = 0; i < 8; ++i)
#pragma unroll
                for (int j = 0; j < 4; ++j)
                    c[i][j] = fmaf(a[i], b[j], c[i][j]);
        }
        __syncthreads();
    }

    float4 bv = *reinterpret_cast<const float4*>(&bias[n0 + tx * 4]);
#pragma unroll
    for (int i = 0; i < 8; ++i) {
        int row = m0 + ty * 8 + i;
        float4 o4;
        o4.x = c[i][0] + bv.x;
        o4.y = c[i][1] + bv.y;
        o4.z = c[i][2] + bv.z;
        o4.w = c[i][3] + bv.w;
        if (EPI == 1) {
            o4.x = fmaxf(o4.x, 0.f); o4.y = fmaxf(o4.y, 0.f);
            o4.z = fmaxf(o4.z, 0.f); o4.w = fmaxf(o4.w, 0.f);
        }
        if (EPI == 3) {
            o4.x *= scale; o4.y *= scale; o4.z *= scale; o4.w *= scale;
            int bb = row >> 9, ss = row & 511;      // row = b*512 + s
            int col = n0 + tx * 4;
            int hh = col >> 6, hd = col & 63;       // col = h*64 + hd
            *reinterpret_cast<float4*>(
                &out[((size_t)(bb * H_ + hh) * S_ + ss) * HD_ + hd]) = o4;
        } else {
            size_t base = (size_t)row * N + n0 + tx * 4;
            if (EPI == 2) {
                float4 rv = *reinterpret_cast<const float4*>(&res[base]);
                o4.x += rv.x; o4.y += rv.y; o4.z += rv.z; o4.w += rv.w;
            }
            *reinterpret_cast<float4*>(&out[base]) = o4;
        }
    }
}

// ------------------------------------------------------------- QK^T + bias
// per b: scores[h,i,j] = sum_d q[b,h,i,d]*k[b,h,j,d] + bias[h,i,j]
// grid (S/64, S/64, H), block 256; K=64 fully LDS-resident.
__launch_bounds__(256)
__global__ void attn_scores(const float* __restrict__ q, const float* __restrict__ k,
                            const float* __restrict__ abias, float* __restrict__ sc, int b)
{
    __shared__ float Qt[64][68];  // [d][i]
    __shared__ float Kt[64][68];  // [d][j]
    const int t  = threadIdx.x;
    const int tx = t & 15, ty = t >> 4;
    const int j0 = blockIdx.x * 64, i0 = blockIdx.y * 64, h = blockIdx.z;
    const float* qb = q + (size_t)(b * H_ + h) * S_ * HD_;
    const float* kb = k + (size_t)(b * H_ + h) * S_ * HD_;
#pragma unroll
    for (int it = 0; it < 4; ++it) {
        int idx = t + it * 256;       // 0..1023
        int r   = idx >> 4;           // 0..63
        int c4  = (idx & 15) << 2;    // 0..60
        float4 v = *reinterpret_cast<const float4*>(&qb[(size_t)(i0 + r) * HD_ + c4]);
        Qt[c4 + 0][r] = v.x; Qt[c4 + 1][r] = v.y; Qt[c4 + 2][r] = v.z; Qt[c4 + 3][r] = v.w;
        float4 w = *reinterpret_cast<const float4*>(&kb[(size_t)(j0 + r) * HD_ + c4]);
        Kt[c4 + 0][r] = w.x; Kt[c4 + 1][r] = w.y; Kt[c4 + 2][r] = w.z; Kt[c4 + 3][r] = w.w;
    }
    __syncthreads();
    float c[4][4] = {};
#pragma unroll 8
    for (int d = 0; d < 64; ++d) {
        float a[4], bb4[4];
        *reinterpret_cast<float4*>(a)   = *reinterpret_cast<const float4*>(&Qt[d][ty * 4]);
        *reinterpret_cast<float4*>(bb4) = *reinterpret_cast<const float4*>(&Kt[d][tx * 4]);
#pragma unroll
        for (int i = 0; i < 4; ++i)
#pragma unroll
            for (int j = 0; j < 4; ++j)
                c[i][j] = fmaf(a[i], bb4[j], c[i][j]);
    }
#pragma unroll
    for (int i = 0; i < 4; ++i) {
        int ig = i0 + ty * 4 + i;
        size_t off = ((size_t)h * S_ + ig) * S_ + j0 + tx * 4;
        float4 bv = *reinterpret_cast<const float4*>(&abias[off]);  // bias broadcast over b
        float4 o4;
        o4.x = c[i][0] + bv.x; o4.y = c[i][1] + bv.y;
        o4.z = c[i][2] + bv.z; o4.w = c[i][3] + bv.w;
        *reinterpret_cast<float4*>(&sc[off]) = o4;
    }
}

// ---------------------------------------------------------------- softmax
// per b: 8192 rows of 512; one wave per row (8 elems/lane)
__launch_bounds__(256)
__global__ void softmax_rows(float* __restrict__ sc)
{
    const int w = threadIdx.x >> 6, lane = threadIdx.x & 63;
    const size_t row = (size_t)blockIdx.x * 4 + w;
    float* p = sc + row * S_ + lane * 8;
    float4 v0 = *reinterpret_cast<const float4*>(p);
    float4 v1 = *reinterpret_cast<const float4*>(p + 4);
    float e[8] = {v0.x, v0.y, v0.z, v0.w, v1.x, v1.y, v1.z, v1.w};
    float mx = e[0];
#pragma unroll
    for (int i = 1; i < 8; ++i) mx = fmaxf(mx, e[i]);
#pragma unroll
    for (int o = 32; o > 0; o >>= 1) mx = fmaxf(mx, __shfl_xor(mx, o));
    float sum = 0.f;
#pragma unroll
    for (int i = 0; i < 8; ++i) { e[i] = __expf(e[i] - mx); sum += e[i]; }
#pragma unroll
    for (int o = 32; o > 0; o >>= 1) sum += __shfl_xor(sum, o);
    const float inv = 1.f / sum;
    v0.x = e[0] * inv; v0.y = e[1] * inv; v0.z = e[2] * inv; v0.w = e[3] * inv;
    v1.x = e[4] * inv; v1.y = e[5] * inv; v1.z = e[6] * inv; v1.w = e[7] * inv;
    *reinterpret_cast<float4*>(p)     = v0;
    *reinterpret_cast<float4*>(p + 4) = v1;
}

// ------------------------------------------------------------------- A @ V
// per b: o[b,s, h*64+hd] = sum_j P[h,s,j] * v[b,h,j,hd]; grid (S/64, H)
__launch_bounds__(256)
__global__ void attn_av(const float* __restrict__ sc, const float* __restrict__ v,
                        float* __restrict__ o, int b)
{
    __shared__ float Pt[32][68];  // [k][i]
    __shared__ float Vs[32][68];  // [k][j]
    const int t  = threadIdx.x;
    const int tx = t & 15, ty = t >> 4;
    const int i0 = blockIdx.x * 64, h = blockIdx.y;
    const float* pb = sc + (size_t)h * S_ * S_;
    const float* vb = v + (size_t)(b * H_ + h) * S_ * HD_;
    float c[4][4] = {};
    for (int kt = 0; kt < S_; kt += 32) {
#pragma unroll
        for (int it = 0; it < 2; ++it) {          // P tile 64x32 transposed
            int idx = t + it * 256;
            int r   = idx >> 3;                   // 0..63 (query row)
            int c4  = (idx & 7) << 2;             // 0..28 (k col)
            float4 a = *reinterpret_cast<const float4*>(&pb[(size_t)(i0 + r) * S_ + kt + c4]);
            Pt[c4 + 0][r] = a.x; Pt[c4 + 1][r] = a.y; Pt[c4 + 2][r] = a.z; Pt[c4 + 3][r] = a.w;
        }
#pragma unroll
        for (int it = 0; it < 2; ++it) {          // V tile 32x64 direct
            int idx = t + it * 256;
            int r   = idx >> 4;                   // 0..31
            int c4  = (idx & 15) << 2;            // 0..60
            *reinterpret_cast<float4*>(&Vs[r][c4]) =
                *reinterpret_cast<const float4*>(&vb[(size_t)(kt + r) * HD_ + c4]);
        }
        __syncthreads();
#pragma unroll 8
        for (int kk = 0; kk < 32; ++kk) {
            float a[4], bb4[4];
            *reinterpret_cast<float4*>(a)   = *reinterpret_cast<const float4*>(&Pt[kk][ty * 4]);
            *reinterpret_cast<float4*>(bb4) = *reinterpret_cast<const float4*>(&Vs[kk][tx * 4]);
#pragma unroll
            for (int i = 0; i < 4; ++i)
#pragma unroll
                for (int j = 0; j < 4; ++j)
                    c[i][j] = fmaf(a[i], bb4[j], c[i][j]);
        }
        __syncthreads();
    }
#pragma unroll
    for (int i = 0; i < 4; ++i) {
        int ig = i0 + ty * 4 + i;
        float4 o4;
        o4.x = c[i][0]; o4.y = c[i][1]; o4.z = c[i][2]; o4.w = c[i][3];
        *reinterpret_cast<float4*>(&o[((size_t)(b * S_ + ig)) * D_ + h * HD_ + tx * 4]) = o4;
    }
}

// ---------------------------------------------------------------- head ops
__launch_bounds__(256)
__global__ void pool_mean(const float* __restrict__ h, float* __restrict__ z)
{
    // grid (8,8): y=b, x=128-col chunk; 2 threads per column, 256 rows each
    __shared__ float red[256];
    const int b = blockIdx.y, d0 = blockIdx.x * 128;
    const int dc = threadIdx.x & 127, sh = threadIdx.x >> 7;
    const float* p = h + ((size_t)b * S_ + sh * 256) * D_ + d0 + dc;
    float s = 0.f;
    for (int i = 0; i < 256; ++i) s += p[(size_t)i * D_];
    red[threadIdx.x] = s;
    __syncthreads();
    if (threadIdx.x < 128)
        z[b * D_ + d0 + dc] = (red[dc] + red[128 + dc]) * (1.f / S_);
}

__launch_bounds__(256)
__global__ void head_fc1(const float* __restrict__ z, const float* __restrict__ W,
                         const float* __restrict__ bi, float* __restrict__ z2)
{
    // grid (16, 8): y=b, x=64-col chunk; 4 threads per col, 256 k each
    __shared__ float zs[D_];
    __shared__ float red[256];
    const int b = blockIdx.y;
    for (int i = threadIdx.x; i < D_; i += 256) zs[i] = z[b * D_ + i];
    __syncthreads();
    const int nc = threadIdx.x & 63;
    const int kq = threadIdx.x >> 6;
    const int n  = blockIdx.x * 64 + nc;
    float acc = 0.f;
    for (int kk = kq * 256; kk < kq * 256 + 256; ++kk)
        acc = fmaf(zs[kk], W[(size_t)kk * D_ + n], acc);
    red[threadIdx.x] = acc;
    __syncthreads();
    if (threadIdx.x < 64) {
        float r = red[nc] + red[64 + nc] + red[128 + nc] + red[192 + nc];
        z2[b * D_ + n] = fmaxf(r + bi[n], 0.f);
    }
}

__global__ void head_fc2(const float* __restrict__ z, const float* __restrict__ W,
                         const float* __restrict__ bi, float* __restrict__ out)
{
    int t = threadIdx.x;
    if (t >= 80) return;
    int b = t / 10, c = t % 10;
    float acc = 0.f;
    for (int kk = 0; kk < D_; ++kk)
        acc = fmaf(z[b * D_ + kk], W[kk * 10 + c], acc);
    out[t] = acc + bi[c];
}

// ---------------------------------------------------------------- launcher
extern "C" void kernel_launch(void* const* d_in, const int* in_sizes, int n_in,
                              void* d_out, int out_size, void* d_ws, size_t ws_size,
                              hipStream_t stream)
{
    const float* x     = (const float*)d_in[0];
    const float* abias = (const float*)d_in[1];
    const float* Wq    = (const float*)d_in[2];
    const float* bq    = (const float*)d_in[3];
    const float* Wk    = (const float*)d_in[4];
    const float* bk    = (const float*)d_in[5];
    const float* Wv    = (const float*)d_in[6];
    const float* bv    = (const float*)d_in[7];
    const float* Wo    = (const float*)d_in[8];
    const float* bo    = (const float*)d_in[9];
    const float* W1    = (const float*)d_in[10];
    const float* b1    = (const float*)d_in[11];
    const float* W2    = (const float*)d_in[12];
    const float* b2    = (const float*)d_in[13];
    const float* g1    = (const float*)d_in[14];
    const float* be1   = (const float*)d_in[15];
    const float* g2    = (const float*)d_in[16];
    const float* be2   = (const float*)d_in[17];
    const float* Wf1   = (const float*)d_in[18];
    const float* bf1   = (const float*)d_in[19];
    const float* gf    = (const float*)d_in[20];
    const float* bfv   = (const float*)d_in[21];
    const float* Wf2   = (const float*)d_in[22];
    const float* bf2   = (const float*)d_in[23];
    float* out = (float*)d_out;

    // workspace layout (floats): h, y(=o), q, k, v : 4M each; big : 16.7M; z, z2
    float* h    = (float*)d_ws;
    float* y    = h    + (size_t)M_ * D_;
    float* q    = y    + (size_t)M_ * D_;
    float* kbuf = q    + (size_t)M_ * D_;
    float* vbuf = kbuf + (size_t)M_ * D_;
    float* big  = vbuf + (size_t)M_ * D_;       // scores (per-b) / FFN mid
    float* z    = big  + (size_t)M_ * DF_;
    float* z2   = z + B_ * D_;

    hipMemcpyAsync(h, x, (size_t)M_ * D_ * sizeof(float), hipMemcpyDeviceToDevice, stream);

    const dim3 blk(256);
    const dim3 gN1024(D_ / 64, M_ / 128);   // (16, 32)
    const dim3 gN4096(DF_ / 64, M_ / 128);  // (64, 32)

    for (int l = 0; l < L_; ++l) {
        const float* wq = Wq + (size_t)l * D_ * D_;
        const float* wk = Wk + (size_t)l * D_ * D_;
        const float* wv = Wv + (size_t)l * D_ * D_;
        const float* wo = Wo + (size_t)l * D_ * D_;
        const float* w1 = W1 + (size_t)l * D_ * DF_;
        const float* w2 = W2 + (size_t)l * DF_ * D_;

        ln_rows<<<M_, blk, 0, stream>>>(h, g1 + l * D_, be1 + l * D_, y);
        gemm_tile<3><<<gN1024, blk, 0, stream>>>(y, wq, bq + l * D_, nullptr, q,    M_, D_, D_, 0.125f);
        gemm_tile<3><<<gN1024, blk, 0, stream>>>(y, wk, bk + l * D_, nullptr, kbuf, M_, D_, D_, 1.f);
        gemm_tile<3><<<gN1024, blk, 0, stream>>>(y, wv, bv + l * D_, nullptr, vbuf, M_, D_, D_, 1.f);

        for (int b = 0; b < B_; ++b) {
            attn_scores<<<dim3(S_ / 64, S_ / 64, H_), blk, 0, stream>>>(q, kbuf, abias, big, b);
            softmax_rows<<<(H_ * S_) / 4, blk, 0, stream>>>(big);
            attn_av<<<dim3(S_ / 64, H_), blk, 0, stream>>>(big, vbuf, y, b);  // o -> y
        }

        gemm_tile<2><<<gN1024, blk, 0, stream>>>(y, wo, bo + l * D_, h, h, M_, D_, D_, 1.f);
        ln_rows<<<M_, blk, 0, stream>>>(h, g2 + l * D_, be2 + l * D_, y);
        gemm_tile<1><<<gN4096, blk, 0, stream>>>(y, w1, b1 + l * DF_, nullptr, big, M_, DF_, D_, 1.f);
        gemm_tile<2><<<gN1024, blk, 0, stream>>>(big, w2, b2 + l * D_, h, h, M_, D_, DF_, 1.f);
    }

    pool_mean<<<dim3(D_ / 128, B_), blk, 0, stream>>>(h, z);
    head_fc1<<<dim3(D_ / 64, B_), blk, 0, stream>>>(z, Wf1, bf1, z2);
    ln_rows<<<B_, blk, 0, stream>>>(z2, gf, bfv, z);
    head_fc2<<<1, 128, 0, stream>>>(z, Wf2, bf2, out);
}